// Round 5
// baseline (441.249 us; speedup 1.0000x reference)
//
#include <hip/hip_runtime.h>
#include <math.h>
#include <stdint.h>

#define NCODES   1024
#define DIM      256
#define NROWS    65536
#define ZQ_ELEMS 16777216
#define MARGIN   2.5e-3f
#define WLCAP    320
#define LDSTRIDE 260

typedef _Float16 f16x8 __attribute__((ext_vector_type(8)));
typedef float    f32x4 __attribute__((ext_vector_type(4)));

// ---- prep: codebook norms (f64->f32), zero counts, f16 codebook in
// MFMA-fragment-linear layout. tile = 128 codes.
// code k = tt*128 + cg*16 + m  (tt=k>>7, cg=(k>>4)&7, m=k&15)
// chunk = ((tt*8+cg)*8 + t)*64 + g*16 + m  holds dims t*32+g*8 .. +7 (8 f16)
__global__ __launch_bounds__(64) void vq_prep(const float* __restrict__ cb,
                                              float* __restrict__ cbnorm,
                                              int* __restrict__ counts,
                                              ushort* __restrict__ cbf) {
    int k = blockIdx.x, l = threadIdx.x;
    float4 e4 = *(const float4*)(cb + (size_t)k * DIM + l * 4);
    double s = (double)e4.x * e4.x + (double)e4.y * e4.y
             + (double)e4.z * e4.z + (double)e4.w * e4.w;
    #pragma unroll
    for (int off = 32; off > 0; off >>= 1) s += __shfl_down(s, off);

    int tt = k >> 7, cg = (k >> 4) & 7, m = k & 15;
    int dim0 = 4 * l;
    int t = dim0 >> 5, g = (dim0 >> 3) & 3, j0 = dim0 & 7;   // j0 in {0,4}
    int chunk = ((tt * 8 + cg) * 8 + t) * 64 + g * 16 + m;
    ushort4 u4;
    u4.x = __builtin_bit_cast(unsigned short, (_Float16)e4.x);
    u4.y = __builtin_bit_cast(unsigned short, (_Float16)e4.y);
    u4.z = __builtin_bit_cast(unsigned short, (_Float16)e4.z);
    u4.w = __builtin_bit_cast(unsigned short, (_Float16)e4.w);
    *(ushort4*)(cbf + (size_t)chunk * 8 + j0) = u4;

    if (l == 0) { cbnorm[k] = (float)s; counts[k] = 0; }
}

// ---- main: 512 threads, M=32 rows, 8 waves x 16 code-cols, reg-B stream ----
__global__ __launch_bounds__(512, 4) void vq_mfma3(
    const float* __restrict__ z, const float* __restrict__ cb,
    const ushort* __restrict__ cbf, const float* __restrict__ cbnorm,
    float* __restrict__ out_zq, float* __restrict__ out_idx,
    int* __restrict__ counts, float* __restrict__ lpart)
{
    __shared__ float zt[32 * 260];          // f32 z tile (exact path)
    __shared__ union UU {
        ushort zth[32 * 264];               // f16 z tile (A-frag source)
        float cbs[256 * 33];                // gathered codebook, [c][r] pad 33
        struct {
            float rrm1[32][8]; int rrk[32][8]; float rrm2[32][8];
            int wlRow[WLCAP]; int wlK[WLCAP]; float wlS[WLCAP];
        } p;
    } u;
    __shared__ float As[32], thr[32];
    __shared__ int amb[32], fb[32], sel[32];
    __shared__ int wlN, fbAll;
    __shared__ float redS[8]; __shared__ int redK[8]; __shared__ float wsum[8];

    const int tid = threadIdx.x;
    const int w = tid >> 6, l = tid & 63;
    const int g = l >> 4, m = l & 15;
    const int blk = blockIdx.x;             // b*32 + h
    const int b = blk >> 5, h = blk & 31;

    const float* zb = z + (size_t)b * 262144 + (size_t)h * 32;

    f16x8 bA[8], bB[8];
    auto load_b = [&](int tt, f16x8 (&dst)[8]) {
        const ushort* src = cbf + (size_t)(tt * 8 + w) * 4096 + (size_t)l * 8;
        #pragma unroll
        for (int t = 0; t < 8; ++t) dst[t] = *(const f16x8*)(src + t * 512);
    };

    load_b(0, bA);   // prefetch B tile 0

    // stage z: f32 -> zt (pad 260), f16 -> zth (pad 264); coalesced float4
    #pragma unroll
    for (int it = 0; it < 4; ++it) {
        int e = it * 512 + tid;
        int c = e >> 3, r4 = e & 7;
        float4 v = *(const float4*)(zb + (size_t)c * 1024 + r4 * 4);
        int r0 = r4 * 4;
        zt[(r0    ) * 260 + c] = v.x;
        zt[(r0 + 1) * 260 + c] = v.y;
        zt[(r0 + 2) * 260 + c] = v.z;
        zt[(r0 + 3) * 260 + c] = v.w;
        u.zth[(r0    ) * 264 + c] = __builtin_bit_cast(unsigned short, (_Float16)v.x);
        u.zth[(r0 + 1) * 264 + c] = __builtin_bit_cast(unsigned short, (_Float16)v.y);
        u.zth[(r0 + 2) * 264 + c] = __builtin_bit_cast(unsigned short, (_Float16)v.z);
        u.zth[(r0 + 3) * 264 + c] = __builtin_bit_cast(unsigned short, (_Float16)v.w);
    }
    __syncthreads();

    // A fragments: rows m and 16+m (every wave holds both rowgroups)
    f16x8 a0[8], a1[8];
    #pragma unroll
    for (int t = 0; t < 8; ++t) {
        a0[t] = *(const f16x8*)(&u.zth[(size_t)m * 264 + t * 32 + g * 8]);
        a1[t] = *(const f16x8*)(&u.zth[(size_t)(16 + m) * 264 + t * 32 + g * 8]);
    }
    if (tid == 0) { wlN = 0; fbAll = 0; }
    if (tid < 32) fb[tid] = 0;
    __syncthreads();   // zth dead -> union reusable (race fix vs r4)

    // per-lane top-2 keys + 3rd value per row-slot
    float s1[8], s2[8], s3[8]; int k1[8], k2[8];
    #pragma unroll
    for (int i = 0; i < 8; ++i) {
        s1[i] = INFINITY; s2[i] = INFINITY; s3[i] = INFINITY; k1[i] = 0; k2[i] = 0;
    }

    auto tile_body = [&](int tt, f16x8 (&bc)[8]) {
        f32x4 acc0 = {0.f, 0.f, 0.f, 0.f}, acc1 = {0.f, 0.f, 0.f, 0.f};
        #pragma unroll
        for (int t = 0; t < 8; ++t) {
            acc0 = __builtin_amdgcn_mfma_f32_16x16x32_f16(a0[t], bc[t], acc0, 0, 0, 0);
            acc1 = __builtin_amdgcn_mfma_f32_16x16x32_f16(a1[t], bc[t], acc1, 0, 0, 0);
        }
        const int kk = tt * 128 + w * 16 + m;
        const float qk = cbnorm[kk];
        #pragma unroll
        for (int j = 0; j < 8; ++j) {
            float sc = fmaf(-2.f, (j < 4 ? acc0[j & 3] : acc1[j & 3]), qk);
            bool lt1 = sc < s1[j];
            bool lt2 = sc < s2[j];
            bool lt3 = sc < s3[j];
            s3[j] = lt2 ? s2[j] : (lt3 ? sc : s3[j]);
            s2[j] = lt1 ? s1[j] : (lt2 ? sc : s2[j]);
            k2[j] = lt1 ? k1[j] : (lt2 ? kk : k2[j]);
            s1[j] = lt1 ? sc : s1[j];
            k1[j] = lt1 ? kk : k1[j];
        }
    };

    // 8 tiles of 128 codes, B prefetched 1 ahead, no barriers
    #pragma unroll 1
    for (int t2 = 0; t2 < 4; ++t2) {
        load_b(2 * t2 + 1, bB);
        tile_body(2 * t2, bA);
        if (t2 < 3) load_b(2 * t2 + 2, bA);
        tile_body(2 * t2 + 1, bB);
    }

    // exact row norms A (f64, identical order to r2/r3/r4; redundant halves
    // write identical values)
    {
        int r = (tid >> 3) & 31, q8 = tid & 7;
        double pa = 0.0;
        #pragma unroll 8
        for (int i = 0; i < 32; ++i) {
            float v = zt[r * 260 + q8 + 8 * i];
            pa += (double)v * (double)v;
        }
        pa += __shfl_down(pa, 4, 8);
        pa += __shfl_down(pa, 2, 8);
        pa += __shfl_down(pa, 1, 8);
        if (q8 == 0) As[r] = (float)pa;
    }

    // per-slot two-min reduce over the 16 lanes sharing a row
    #pragma unroll
    for (int si = 0; si < 8; ++si) {
        float v1 = s1[si]; int kk = k1[si]; float v2 = s2[si];
        #pragma unroll
        for (int mk = 1; mk < 16; mk <<= 1) {
            float o1 = __shfl_xor(v1, mk, 16);
            int   ok = __shfl_xor(kk, mk, 16);
            float o2 = __shfl_xor(v2, mk, 16);
            bool take = (o1 < v1) || (o1 == v1 && ok < kk);
            float nm2 = fminf(fmaxf(o1, v1), fminf(o2, v2));
            if (take) { v1 = o1; kk = ok; }
            v2 = nm2;
        }
        if (m == 0) {
            int row = (si >> 2) * 16 + g * 4 + (si & 3);
            u.p.rrm1[row][w] = v1; u.p.rrk[row][w] = kk; u.p.rrm2[row][w] = v2;
        }
    }
    __syncthreads();

    // merge 8 wave-partials per row; threshold & ambiguity
    if (tid < 32) {
        float M1 = u.p.rrm1[tid][0]; int K1 = u.p.rrk[tid][0]; float M2 = u.p.rrm2[tid][0];
        #pragma unroll
        for (int q = 1; q < 8; ++q) {
            float o1 = u.p.rrm1[tid][q]; int ok = u.p.rrk[tid][q]; float o2 = u.p.rrm2[tid][q];
            bool take = (o1 < M1) || (o1 == M1 && ok < K1);
            float nm2 = fminf(fmaxf(o1, M1), fminf(o2, M2));
            if (take) { M1 = o1; K1 = ok; }
            M2 = nm2;
        }
        float th_ = M1 + MARGIN;
        thr[tid] = th_; amb[tid] = (M2 <= th_) ? 1 : 0;
        sel[tid] = K1;                      // final for unambiguous rows
    }
    __syncthreads();

    // append in-margin candidates (both keys); 3rd-in-margin -> row fallback
    #pragma unroll
    for (int si = 0; si < 8; ++si) {
        int row = (si >> 2) * 16 + g * 4 + (si & 3);
        if (amb[row]) {
            float th_ = thr[row];
            if (s3[si] <= th_) fb[row] = 1;
            if (s2[si] <= th_) {
                int pos = atomicAdd(&wlN, 1);
                if (pos < WLCAP) { u.p.wlRow[pos] = row; u.p.wlK[pos] = k2[si]; }
                else fbAll = 1;
            }
            if (s1[si] <= th_) {
                int pos = atomicAdd(&wlN, 1);
                if (pos < WLCAP) { u.p.wlRow[pos] = row; u.p.wlK[pos] = k1[si]; }
                else fbAll = 1;
            }
        }
    }
    __syncthreads();

    // exact rescore (bit-identical to the r2 np-f32 pipeline)
    auto rescore = [&](int row, int k) -> float {
        const float* e  = cb + (size_t)k * 256;
        const float* zr = zt + row * 260;
        float ax = 0.f, ay = 0.f, az = 0.f, aw = 0.f;
        #pragma unroll 8
        for (int d4 = 0; d4 < 64; ++d4) {
            float4 ev = *(const float4*)(e + d4 * 4);
            ax = fmaf(zr[d4 * 4    ], ev.x, ax);
            ay = fmaf(zr[d4 * 4 + 1], ev.y, ay);
            az = fmaf(zr[d4 * 4 + 2], ev.z, az);
            aw = fmaf(zr[d4 * 4 + 3], ev.w, aw);
        }
        float dot = __fadd_rn(__fadd_rn(ax, ay), __fadd_rn(az, aw));
        return __fsub_rn(__fadd_rn(As[row], cbnorm[k]), __fmul_rn(2.f, dot));
    };

    int nw = wlN; nw = nw > WLCAP ? WLCAP : nw;
    for (int i = tid; i < nw; i += 512)
        u.p.wlS[i] = rescore(u.p.wlRow[i], u.p.wlK[i]);
    __syncthreads();

    // per-row merge of rescored candidates (min, lowest-k tie-break)
    if (tid < 32 && amb[tid]) {
        if (fbAll) fb[tid] = 1;
        if (!fb[tid]) {
            float bs = INFINITY; int bk = 0x7fffffff; int found = 0;
            for (int i = 0; i < nw; ++i) {
                if (u.p.wlRow[i] == tid) {
                    float ss = u.p.wlS[i]; int kk = u.p.wlK[i];
                    if (ss < bs || (ss == bs && kk < bk)) { bs = ss; bk = kk; }
                    found = 1;
                }
            }
            if (found) sel[tid] = bk; else fb[tid] = 1;
        }
    }
    __syncthreads();

    // fallback: guaranteed-exact full scan (rare; block-uniform branch)
    for (int r = 0; r < 32; ++r) {
        if (fb[r]) {
            float bsf = INFINITY; int bkf = 0x7fffffff;
            for (int kk = tid; kk < NCODES; kk += 512) {
                float ss = rescore(r, kk);
                if (ss < bsf || (ss == bsf && kk < bkf)) { bsf = ss; bkf = kk; }
            }
            #pragma unroll
            for (int off = 32; off > 0; off >>= 1) {
                float os = __shfl_down(bsf, off); int okk = __shfl_down(bkf, off);
                if (os < bsf || (os == bsf && okk < bkf)) { bsf = os; bkf = okk; }
            }
            if (l == 0) { redS[w] = bsf; redK[w] = bkf; }
            __syncthreads();
            if (tid == 0) {
                float bs2 = redS[0]; int bk2 = redK[0];
                for (int i = 1; i < 8; ++i) {
                    float os = redS[i]; int okk = redK[i];
                    if (os < bs2 || (os == bs2 && okk < bk2)) { bs2 = os; bk2 = okk; }
                }
                sel[r] = bk2;
            }
            __syncthreads();
        }
    }
    __syncthreads();   // sel final; union p dead -> cbs reusable

    // indices + histogram
    if (tid < 32) {
        int sv = sel[tid];
        out_idx[blk * 32 + tid] = (float)sv;
        atomicAdd(&counts[sv], 1);
    }

    // gather: coalesced codebook rows -> cbs[c][r] (conflict-free); fused loss
    float lacc = 0.f;
    #pragma unroll
    for (int ri = 0; ri < 4; ++ri) {
        int row = ri * 8 + w;
        int sv = sel[row];
        float4 cv = *(const float4*)(cb + (size_t)sv * 256 + l * 4);
        float4 zv = *(const float4*)(&zt[row * 260 + l * 4]);
        lacc = fmaf(cv.x - zv.x, cv.x - zv.x, lacc);
        lacc = fmaf(cv.y - zv.y, cv.y - zv.y, lacc);
        lacc = fmaf(cv.z - zv.z, cv.z - zv.z, lacc);
        lacc = fmaf(cv.w - zv.w, cv.w - zv.w, lacc);
        u.cbs[(4 * l    ) * 33 + row] = cv.x;
        u.cbs[(4 * l + 1) * 33 + row] = cv.y;
        u.cbs[(4 * l + 2) * 33 + row] = cv.z;
        u.cbs[(4 * l + 3) * 33 + row] = cv.w;
    }
    #pragma unroll
    for (int off = 32; off > 0; off >>= 1) lacc += __shfl_down(lacc, off);
    if (l == 0) wsum[w] = lacc;
    __syncthreads();

    // coalesced z_q output (full 128B lines: lanes 0-31 cover r=0..31)
    float* ob = out_zq + (size_t)b * 262144 + (size_t)h * 32;
    #pragma unroll 4
    for (int it = 0; it < 16; ++it) {
        int e = it * 512 + tid;
        int c = e >> 5, r = e & 31;
        ob[(size_t)c * 1024 + r] = u.cbs[c * 33 + r];
    }
    if (tid == 0) {
        float t = 0.f;
        #pragma unroll
        for (int i = 0; i < 8; ++i) t += wsum[i];
        lpart[blk] = t;
    }
}

// ---- finalize: loss + perplexity ----
__global__ __launch_bounds__(256) void vq_finalize(const float* __restrict__ lpart,
                                                   const int* __restrict__ counts,
                                                   float* __restrict__ out_scalars,
                                                   int nblk) {
    __shared__ double sd[256];
    const int tid = threadIdx.x;
    double s = 0.0;
    for (int i = tid; i < nblk; i += 256) s += (double)lpart[i];
    sd[tid] = s;
    __syncthreads();
    #pragma unroll
    for (int st = 128; st > 0; st >>= 1) {
        if (tid < st) sd[tid] += sd[tid + st];
        __syncthreads();
    }
    double loss = 0.0;
    if (tid == 0) loss = 0.25 * sd[0] / (double)ZQ_ELEMS;
    __syncthreads();
    double e = 0.0;
    for (int i = tid; i < NCODES; i += 256) {
        float p = (float)counts[i] / (float)NROWS;
        e += (double)(p * logf(p + 1e-10f));
    }
    sd[tid] = e;
    __syncthreads();
    #pragma unroll
    for (int st = 128; st > 0; st >>= 1) {
        if (tid < st) sd[tid] += sd[tid + st];
        __syncthreads();
    }
    if (tid == 0) {
        out_scalars[0] = (float)loss;
        out_scalars[1] = expf((float)(-sd[0]));
    }
}

// ================= round-2 fallback path (used only if ws too small) ========
__global__ __launch_bounds__(64) void vq_norms(const float* __restrict__ cb,
                                               float* __restrict__ q,
                                               int* __restrict__ counts) {
    int k = blockIdx.x;
    int lane = threadIdx.x;
    float4 e4 = *(const float4*)(cb + (size_t)k * DIM + lane * 4);
    double s = (double)e4.x * e4.x + (double)e4.y * e4.y
             + (double)e4.z * e4.z + (double)e4.w * e4.w;
    #pragma unroll
    for (int off = 32; off > 0; off >>= 1) s += __shfl_down(s, off);
    if (lane == 0) { q[k] = (float)s; counts[k] = 0; }
}

__global__ __launch_bounds__(256) void vq_main_r2(const float* __restrict__ z,
                                                  const float* __restrict__ cb,
                                                  const float* __restrict__ q,
                                                  float* __restrict__ out_zq,
                                                  float* __restrict__ out_idx,
                                                  int* __restrict__ counts,
                                                  float* __restrict__ lpart) {
    __shared__ float zt[32][LDSTRIDE];
    __shared__ float sbest[32][8];
    __shared__ int   kbest[32][8];
    __shared__ int   sel[32];
    __shared__ float lred[256];

    const int blk = blockIdx.x;
    const int b   = blk >> 5;
    const int h   = blk & 31;
    const int tid = threadIdx.x;
    const float* zb = z + (size_t)b * 262144 + (size_t)h * 32;

    #pragma unroll
    for (int it = 0; it < 32; ++it) {
        int e = it * 256 + tid;
        int d = e >> 5, ww = e & 31;
        zt[ww][d] = zb[(size_t)d * 1024 + ww];
    }
    __syncthreads();

    const int r    = tid >> 3;
    const int lane = tid & 7;
    const float4* zr = (const float4*)(&zt[r][0]);

    double pa = 0.0;
    #pragma unroll 8
    for (int i = 0; i < 32; ++i) {
        float v = zt[r][lane + 8 * i];
        pa += (double)v * (double)v;
    }
    pa += __shfl_down(pa, 4, 8);
    pa += __shfl_down(pa, 2, 8);
    pa += __shfl_down(pa, 1, 8);
    pa = __shfl(pa, 0, 8);
    const float A = (float)pa;

    float best = INFINITY;
    int   bk   = 0;
    for (int j = 0; j < 64; ++j) {
        const int kk1 = lane + 8 * j;
        const int kk2 = kk1 + 512;
        const float4* e1 = (const float4*)(cb + (size_t)kk1 * DIM);
        const float4* e2 = (const float4*)(cb + (size_t)kk2 * DIM);
        float a1x = 0.f, a1y = 0.f, a1z = 0.f, a1w = 0.f;
        float a2x = 0.f, a2y = 0.f, a2z = 0.f, a2w = 0.f;
        #pragma unroll 16
        for (int d4 = 0; d4 < DIM / 4; ++d4) {
            float4 zv = zr[d4];
            float4 v1 = e1[d4];
            float4 v2 = e2[d4];
            a1x = fmaf(zv.x, v1.x, a1x); a1y = fmaf(zv.y, v1.y, a1y);
            a1z = fmaf(zv.z, v1.z, a1z); a1w = fmaf(zv.w, v1.w, a1w);
            a2x = fmaf(zv.x, v2.x, a2x); a2y = fmaf(zv.y, v2.y, a2y);
            a2z = fmaf(zv.z, v2.z, a2z); a2w = fmaf(zv.w, v2.w, a2w);
        }
        float dot1 = __fadd_rn(__fadd_rn(a1x, a1y), __fadd_rn(a1z, a1w));
        float dot2 = __fadd_rn(__fadd_rn(a2x, a2y), __fadd_rn(a2z, a2w));
        float sc1 = __fsub_rn(__fadd_rn(A, q[kk1]), __fmul_rn(2.f, dot1));
        float sc2 = __fsub_rn(__fadd_rn(A, q[kk2]), __fmul_rn(2.f, dot2));
        if (sc1 < best || (sc1 == best && kk1 < bk)) { best = sc1; bk = kk1; }
        if (sc2 < best || (sc2 == best && kk2 < bk)) { best = sc2; bk = kk2; }
    }
    sbest[r][lane] = best;
    kbest[r][lane] = bk;
    __syncthreads();

    if (tid < 32) {
        float bb = sbest[tid][0];
        int   bi = kbest[tid][0];
        #pragma unroll
        for (int ll = 1; ll < 8; ++ll) {
            float s = sbest[tid][ll]; int kk = kbest[tid][ll];
            if (s < bb || (s == bb && kk < bi)) { bb = s; bi = kk; }
        }
        sel[tid] = bi;
        out_idx[blk * 32 + tid] = (float)bi;
        atomicAdd(&counts[bi], 1);
    }
    __syncthreads();

    float lacc = 0.f;
    float* ob = out_zq + (size_t)b * 262144 + (size_t)h * 32;
    #pragma unroll
    for (int it = 0; it < 32; ++it) {
        int e = it * 256 + tid;
        int c = e >> 5, ww = e & 31;
        float cv = cb[(size_t)sel[ww] * DIM + c];
        float dz = cv - zt[ww][c];
        lacc = fmaf(dz, dz, lacc);
        ob[(size_t)c * 1024 + ww] = cv;
    }
    lred[tid] = lacc;
    __syncthreads();
    #pragma unroll
    for (int s = 128; s > 0; s >>= 1) {
        if (tid < s) lred[tid] += lred[tid + s];
        __syncthreads();
    }
    if (tid == 0) lpart[blk] = lred[0];
}

extern "C" void kernel_launch(void* const* d_in, const int* in_sizes, int n_in,
                              void* d_out, int out_size, void* d_ws, size_t ws_size,
                              hipStream_t stream) {
    const float* z  = (const float*)d_in[0];          // [64,256,32,32]
    const float* cb = (const float*)d_in[1];          // [1024,256]

    float* out_zq      = (float*)d_out;               // 16777216
    float* out_idx     = out_zq + ZQ_ELEMS;           // 65536
    float* out_scalars = out_idx + NROWS;             // loss, perplexity

    float*  q      = (float*)d_ws;                    // 1024 f32
    int*    counts = (int*)(q + NCODES);              // 1024 i32
    float*  lpart  = (float*)(counts + NCODES);       // 2048 f32
    ushort* cbf    = (ushort*)((char*)d_ws + 16384);  // 512 KB frag-linear f16

    bool mfma_ok = ws_size >= (size_t)(16384 + NCODES * DIM * 2);

    if (mfma_ok) {
        vq_prep<<<NCODES, 64, 0, stream>>>(cb, q, counts, cbf);
        vq_mfma3<<<NROWS / 32, 512, 0, stream>>>(z, cb, cbf, q, out_zq, out_idx, counts, lpart);
        vq_finalize<<<1, 256, 0, stream>>>(lpart, counts, out_scalars, NROWS / 32);
    } else {
        vq_norms<<<NCODES, 64, 0, stream>>>(cb, q, counts);
        vq_main_r2<<<NROWS / 32, 256, 0, stream>>>(z, cb, q, out_zq, out_idx, counts, lpart);
        vq_finalize<<<1, 256, 0, stream>>>(lpart, counts, out_scalars, NROWS / 32);
    }
}

// Round 6
// 194.348 us; speedup vs baseline: 2.2704x; 2.2704x over previous
//
#include <hip/hip_runtime.h>
#include <math.h>
#include <stdint.h>

#define NCODES   1024
#define DIM      256
#define NROWS    65536
#define ZQ_ELEMS 16777216
#define DMARGIN  1.25e-3f     // dot-space margin (worst-case f16 filter err ~7.4e-4)
#define WLCAP    320
#define LDSTRIDE 260

typedef _Float16 f16x8 __attribute__((ext_vector_type(8)));
typedef float    f32x4 __attribute__((ext_vector_type(4)));

// ---- prep: codebook norms (f64->f32), zero counts, f16 codebook in
// MFMA-fragment-linear layout (64-code tiles; identical to round 4).
// code k = tt*64 + cg*16 + m ; chunk = ((tt*4+cg)*8 + t)*64 + g*16 + m
// holds dims t*32+g*8 .. +7 (8 f16).
__global__ __launch_bounds__(64) void vq_prep(const float* __restrict__ cb,
                                              float* __restrict__ cbnorm,
                                              int* __restrict__ counts,
                                              ushort* __restrict__ cbf) {
    int k = blockIdx.x, l = threadIdx.x;
    float4 e4 = *(const float4*)(cb + (size_t)k * DIM + l * 4);
    double s = (double)e4.x * e4.x + (double)e4.y * e4.y
             + (double)e4.z * e4.z + (double)e4.w * e4.w;
    #pragma unroll
    for (int off = 32; off > 0; off >>= 1) s += __shfl_down(s, off);

    int tt = k >> 6, cg = (k >> 4) & 3, m = k & 15;
    int dim0 = 4 * l;
    int t = dim0 >> 5, g = (dim0 >> 3) & 3, j0 = dim0 & 7;   // j0 in {0,4}
    int chunk = ((tt * 4 + cg) * 8 + t) * 64 + g * 16 + m;
    ushort4 u4;
    u4.x = __builtin_bit_cast(unsigned short, (_Float16)e4.x);
    u4.y = __builtin_bit_cast(unsigned short, (_Float16)e4.y);
    u4.z = __builtin_bit_cast(unsigned short, (_Float16)e4.z);
    u4.w = __builtin_bit_cast(unsigned short, (_Float16)e4.w);
    *(ushort4*)(cbf + (size_t)chunk * 8 + j0) = u4;

    if (l == 0) { cbnorm[k] = (float)s; counts[k] = 0; }
}

// ---- main: 256 thr, M=32, reg-resident A, dbuf reg-B, max-dot filter ----
__global__ __launch_bounds__(256, 2) void vq_mfma4(
    const float* __restrict__ z, const float* __restrict__ cb,
    const ushort* __restrict__ cbf, const float* __restrict__ cbnorm,
    float* __restrict__ out_zq, float* __restrict__ out_idx,
    int* __restrict__ counts, float* __restrict__ lpart)
{
    __shared__ float zt[32 * 260];          // f32 z tile (filter A + exact path)
    __shared__ union UU {
        struct {
            float rrm1[32][4]; int rrk[32][4]; float rrm2[32][4];
            int wlRow[WLCAP]; int wlK[WLCAP]; float wlS[WLCAP];
        } p;
        float cbs[64 * 33];                 // quarter transpose buffer
    } u;
    __shared__ float As[32], thr[32];
    __shared__ int amb[32], fb[32], sel[32];
    __shared__ int wlN, fbAll;
    __shared__ float redS[4]; __shared__ int redK[4]; __shared__ float wsum[4];

    const int tid = threadIdx.x;
    const int w = tid >> 6, l = tid & 63;
    const int g = l >> 4, m = l & 15;
    const int blk = blockIdx.x;             // b*32 + h
    const int b = blk >> 5, h = blk & 31;

    const float* zb = z + (size_t)b * 262144 + (size_t)h * 32;

    f16x8 bA[8], bB[8];
    auto load_b = [&](int tt, f16x8 (&dst)[8]) {
        const ushort* src = cbf + (size_t)(tt * 4 + w) * 4096 + (size_t)l * 8;
        #pragma unroll
        for (int t = 0; t < 8; ++t) dst[t] = *(const f16x8*)(src + t * 512);
    };

    load_b(0, bA);   // prefetch B tile 0 (overlaps staging)

    // stage z: f32 tile only; coalesced float4 along r
    #pragma unroll
    for (int it = 0; it < 8; ++it) {
        int e = it * 256 + tid;
        int c = e >> 3, r4 = e & 7;
        float4 v = *(const float4*)(zb + (size_t)c * 1024 + r4 * 4);
        int r0 = r4 * 4;
        zt[(r0    ) * 260 + c] = v.x;
        zt[(r0 + 1) * 260 + c] = v.y;
        zt[(r0 + 2) * 260 + c] = v.z;
        zt[(r0 + 3) * 260 + c] = v.w;
    }
    if (tid == 0) { wlN = 0; fbAll = 0; }
    if (tid < 32) fb[tid] = 0;
    __syncthreads();

    // A fragments from f32 LDS + cvt (one-time); forced register-resident
    f16x8 a0[8], a1[8];
    #pragma unroll
    for (int t = 0; t < 8; ++t) {
        const float* p0 = zt + (size_t)m * 260 + t * 32 + g * 8;
        const float* p1 = zt + (size_t)(16 + m) * 260 + t * 32 + g * 8;
        float4 v0 = *(const float4*)(p0), v1 = *(const float4*)(p0 + 4);
        float4 w0 = *(const float4*)(p1), w1 = *(const float4*)(p1 + 4);
        f16x8 fa, fb_;
        fa[0] = (_Float16)v0.x; fa[1] = (_Float16)v0.y;
        fa[2] = (_Float16)v0.z; fa[3] = (_Float16)v0.w;
        fa[4] = (_Float16)v1.x; fa[5] = (_Float16)v1.y;
        fa[6] = (_Float16)v1.z; fa[7] = (_Float16)v1.w;
        fb_[0] = (_Float16)w0.x; fb_[1] = (_Float16)w0.y;
        fb_[2] = (_Float16)w0.z; fb_[3] = (_Float16)w0.w;
        fb_[4] = (_Float16)w1.x; fb_[5] = (_Float16)w1.y;
        fb_[6] = (_Float16)w1.z; fb_[7] = (_Float16)w1.w;
        a0[t] = fa; a1[t] = fb_;
    }

    // per-lane top-2 keys + 3rd value per row-slot, MAX-dot space
    float s1[8], s2[8], s3[8]; int k1[8], k2[8];
    #pragma unroll
    for (int i = 0; i < 8; ++i) {
        s1[i] = -INFINITY; s2[i] = -INFINITY; s3[i] = -INFINITY; k1[i] = 0; k2[i] = 0;
    }

    auto tile_body = [&](int tt, f16x8 (&bc)[8]) {
        // 4 independent chains of depth 4 (even/odd K per rowgroup)
        f32x4 p0 = {0,0,0,0}, q0 = {0,0,0,0}, p1 = {0,0,0,0}, q1 = {0,0,0,0};
        #pragma unroll
        for (int t = 0; t < 8; t += 2) {
            p0 = __builtin_amdgcn_mfma_f32_16x16x32_f16(a0[t],     bc[t],     p0, 0, 0, 0);
            p1 = __builtin_amdgcn_mfma_f32_16x16x32_f16(a1[t],     bc[t],     p1, 0, 0, 0);
            q0 = __builtin_amdgcn_mfma_f32_16x16x32_f16(a0[t + 1], bc[t + 1], q0, 0, 0, 0);
            q1 = __builtin_amdgcn_mfma_f32_16x16x32_f16(a1[t + 1], bc[t + 1], q1, 0, 0, 0);
        }
        const int kk = tt * 64 + w * 16 + m;
        #pragma unroll
        for (int j = 0; j < 8; ++j) {
            float d = (j < 4) ? (p0[j & 3] + q0[j & 3]) : (p1[j & 3] + q1[j & 3]);
            bool lt1 = d > s1[j];
            bool lt2 = d > s2[j];
            s3[j] = fminf(fmaxf(d, s3[j]), s2[j]);   // med3 max-space
            s2[j] = fminf(fmaxf(d, s2[j]), s1[j]);
            k2[j] = lt1 ? k1[j] : (lt2 ? kk : k2[j]);
            k1[j] = lt1 ? kk : k1[j];
            s1[j] = fmaxf(d, s1[j]);
        }
    };

    // 16 tiles of 64 codes, reg-B double-buffered, no barriers
    #pragma unroll 1
    for (int t2 = 0; t2 < 8; ++t2) {
        load_b(2 * t2 + 1, bB);
        tile_body(2 * t2, bA);
        if (t2 < 7) load_b(2 * t2 + 2, bA);
        tile_body(2 * t2 + 1, bB);
    }

    // exact row norms A (f64, bit-identical order to r2..r5)
    {
        int r = tid >> 3, q8 = tid & 7;
        double pa = 0.0;
        #pragma unroll 8
        for (int i = 0; i < 32; ++i) {
            float v = zt[r * 260 + q8 + 8 * i];
            pa += (double)v * (double)v;
        }
        pa += __shfl_down(pa, 4, 8);
        pa += __shfl_down(pa, 2, 8);
        pa += __shfl_down(pa, 1, 8);
        if (q8 == 0) As[r] = (float)pa;
    }

    // per-slot two-MAX reduce over the 16 lanes sharing a row
    #pragma unroll
    for (int si = 0; si < 8; ++si) {
        float v1 = s1[si]; int kk = k1[si]; float v2 = s2[si];
        #pragma unroll
        for (int mk = 1; mk < 16; mk <<= 1) {
            float o1 = __shfl_xor(v1, mk, 16);
            int   ok = __shfl_xor(kk, mk, 16);
            float o2 = __shfl_xor(v2, mk, 16);
            bool take = (o1 > v1) || (o1 == v1 && ok < kk);
            float nm2 = fmaxf(fminf(o1, v1), fmaxf(o2, v2));
            if (take) { v1 = o1; kk = ok; }
            v2 = nm2;
        }
        if (m == 0) {
            int row = (si >> 2) * 16 + g * 4 + (si & 3);
            u.p.rrm1[row][w] = v1; u.p.rrk[row][w] = kk; u.p.rrm2[row][w] = v2;
        }
    }
    __syncthreads();

    // merge 4 wave-partials per row; threshold & ambiguity (max-dot space)
    if (tid < 32) {
        float M1 = u.p.rrm1[tid][0]; int K1 = u.p.rrk[tid][0]; float M2 = u.p.rrm2[tid][0];
        #pragma unroll
        for (int q = 1; q < 4; ++q) {
            float o1 = u.p.rrm1[tid][q]; int ok = u.p.rrk[tid][q]; float o2 = u.p.rrm2[tid][q];
            bool take = (o1 > M1) || (o1 == M1 && ok < K1);
            float nm2 = fmaxf(fminf(o1, M1), fmaxf(o2, M2));
            if (take) { M1 = o1; K1 = ok; }
            M2 = nm2;
        }
        float th_ = M1 - DMARGIN;
        thr[tid] = th_; amb[tid] = (M2 >= th_) ? 1 : 0;
        sel[tid] = K1;                      // final for unambiguous rows
    }
    __syncthreads();

    // append in-margin candidates (both keys); 3rd-in-margin -> row fallback
    #pragma unroll
    for (int si = 0; si < 8; ++si) {
        int row = (si >> 2) * 16 + g * 4 + (si & 3);
        if (amb[row]) {
            float th_ = thr[row];
            if (s3[si] >= th_) fb[row] = 1;
            if (s2[si] >= th_) {
                int pos = atomicAdd(&wlN, 1);
                if (pos < WLCAP) { u.p.wlRow[pos] = row; u.p.wlK[pos] = k2[si]; }
                else fbAll = 1;
            }
            if (s1[si] >= th_) {
                int pos = atomicAdd(&wlN, 1);
                if (pos < WLCAP) { u.p.wlRow[pos] = row; u.p.wlK[pos] = k1[si]; }
                else fbAll = 1;
            }
        }
    }
    __syncthreads();

    // exact rescore (bit-identical to the r2 np-f32 pipeline)
    auto rescore = [&](int row, int k) -> float {
        const float* e  = cb + (size_t)k * 256;
        const float* zr = zt + row * 260;
        float ax = 0.f, ay = 0.f, az = 0.f, aw = 0.f;
        #pragma unroll 8
        for (int d4 = 0; d4 < 64; ++d4) {
            float4 ev = *(const float4*)(e + d4 * 4);
            ax = fmaf(zr[d4 * 4    ], ev.x, ax);
            ay = fmaf(zr[d4 * 4 + 1], ev.y, ay);
            az = fmaf(zr[d4 * 4 + 2], ev.z, az);
            aw = fmaf(zr[d4 * 4 + 3], ev.w, aw);
        }
        float dot = __fadd_rn(__fadd_rn(ax, ay), __fadd_rn(az, aw));
        return __fsub_rn(__fadd_rn(As[row], cbnorm[k]), __fmul_rn(2.f, dot));
    };

    int nw = wlN; nw = nw > WLCAP ? WLCAP : nw;
    for (int i = tid; i < nw; i += 256)
        u.p.wlS[i] = rescore(u.p.wlRow[i], u.p.wlK[i]);
    __syncthreads();

    // per-row merge of rescored candidates (min score, lowest-k tie-break)
    if (tid < 32 && amb[tid]) {
        if (fbAll) fb[tid] = 1;
        if (!fb[tid]) {
            float bs = INFINITY; int bk = 0x7fffffff; int found = 0;
            for (int i = 0; i < nw; ++i) {
                if (u.p.wlRow[i] == tid) {
                    float ss = u.p.wlS[i]; int kk = u.p.wlK[i];
                    if (ss < bs || (ss == bs && kk < bk)) { bs = ss; bk = kk; }
                    found = 1;
                }
            }
            if (found) sel[tid] = bk; else fb[tid] = 1;
        }
    }
    __syncthreads();

    // fallback: guaranteed-exact full scan (rare; block-uniform branch)
    for (int r = 0; r < 32; ++r) {
        if (fb[r]) {
            float bsf = INFINITY; int bkf = 0x7fffffff;
            for (int kk = tid; kk < NCODES; kk += 256) {
                float ss = rescore(r, kk);
                if (ss < bsf || (ss == bsf && kk < bkf)) { bsf = ss; bkf = kk; }
            }
            #pragma unroll
            for (int off = 32; off > 0; off >>= 1) {
                float os = __shfl_down(bsf, off); int okk = __shfl_down(bkf, off);
                if (os < bsf || (os == bsf && okk < bkf)) { bsf = os; bkf = okk; }
            }
            if (l == 0) { redS[w] = bsf; redK[w] = bkf; }
            __syncthreads();
            if (tid == 0) {
                float bs2 = redS[0]; int bk2 = redK[0];
                for (int i = 1; i < 4; ++i) {
                    float os = redS[i]; int okk = redK[i];
                    if (os < bs2 || (os == bs2 && okk < bk2)) { bs2 = os; bk2 = okk; }
                }
                sel[r] = bk2;
            }
            __syncthreads();
        }
    }
    __syncthreads();   // sel final; union p dead -> cbs reusable

    // indices + histogram
    if (tid < 32) {
        int sv = sel[tid];
        out_idx[blk * 32 + tid] = (float)sv;
        atomicAdd(&counts[sv], 1);
    }

    // epilogue: 4 quarter-passes, gather + loss + conflict-free transpose out
    float lacc = 0.f;
    float* ob = out_zq + (size_t)b * 262144 + (size_t)h * 32;
    #pragma unroll 1
    for (int q = 0; q < 4; ++q) {
        int row = tid >> 3, c8 = tid & 7;
        int c = q * 64 + c8 * 8;
        int sv = sel[row];
        float4 cv0 = *(const float4*)(cb + (size_t)sv * 256 + c);
        float4 cv1 = *(const float4*)(cb + (size_t)sv * 256 + c + 4);
        float4 zv0 = *(const float4*)(&zt[row * 260 + c]);
        float4 zv1 = *(const float4*)(&zt[row * 260 + c + 4]);
        lacc = fmaf(cv0.x - zv0.x, cv0.x - zv0.x, lacc);
        lacc = fmaf(cv0.y - zv0.y, cv0.y - zv0.y, lacc);
        lacc = fmaf(cv0.z - zv0.z, cv0.z - zv0.z, lacc);
        lacc = fmaf(cv0.w - zv0.w, cv0.w - zv0.w, lacc);
        lacc = fmaf(cv1.x - zv1.x, cv1.x - zv1.x, lacc);
        lacc = fmaf(cv1.y - zv1.y, cv1.y - zv1.y, lacc);
        lacc = fmaf(cv1.z - zv1.z, cv1.z - zv1.z, lacc);
        lacc = fmaf(cv1.w - zv1.w, cv1.w - zv1.w, lacc);
        int cl = c8 * 8;
        u.cbs[(cl    ) * 33 + row] = cv0.x;
        u.cbs[(cl + 1) * 33 + row] = cv0.y;
        u.cbs[(cl + 2) * 33 + row] = cv0.z;
        u.cbs[(cl + 3) * 33 + row] = cv0.w;
        u.cbs[(cl + 4) * 33 + row] = cv1.x;
        u.cbs[(cl + 5) * 33 + row] = cv1.y;
        u.cbs[(cl + 6) * 33 + row] = cv1.z;
        u.cbs[(cl + 7) * 33 + row] = cv1.w;
        __syncthreads();
        #pragma unroll
        for (int it = 0; it < 8; ++it) {
            int e = it * 256 + tid;
            int cl2 = e >> 5, r = e & 31;
            ob[(size_t)(q * 64 + cl2) * 1024 + r] = u.cbs[cl2 * 33 + r];
        }
        __syncthreads();
    }
    #pragma unroll
    for (int off = 32; off > 0; off >>= 1) lacc += __shfl_down(lacc, off);
    if (l == 0) wsum[w] = lacc;
    __syncthreads();
    if (tid == 0) lpart[blk] = wsum[0] + wsum[1] + wsum[2] + wsum[3];
}

// ---- finalize: loss + perplexity ----
__global__ __launch_bounds__(256) void vq_finalize(const float* __restrict__ lpart,
                                                   const int* __restrict__ counts,
                                                   float* __restrict__ out_scalars,
                                                   int nblk) {
    __shared__ double sd[256];
    const int tid = threadIdx.x;
    double s = 0.0;
    for (int i = tid; i < nblk; i += 256) s += (double)lpart[i];
    sd[tid] = s;
    __syncthreads();
    #pragma unroll
    for (int st = 128; st > 0; st >>= 1) {
        if (tid < st) sd[tid] += sd[tid + st];
        __syncthreads();
    }
    double loss = 0.0;
    if (tid == 0) loss = 0.25 * sd[0] / (double)ZQ_ELEMS;
    __syncthreads();
    double e = 0.0;
    for (int i = tid; i < NCODES; i += 256) {
        float p = (float)counts[i] / (float)NROWS;
        e += (double)(p * logf(p + 1e-10f));
    }
    sd[tid] = e;
    __syncthreads();
    #pragma unroll
    for (int st = 128; st > 0; st >>= 1) {
        if (tid < st) sd[tid] += sd[tid + st];
        __syncthreads();
    }
    if (tid == 0) {
        out_scalars[0] = (float)loss;
        out_scalars[1] = expf((float)(-sd[0]));
    }
}

// ================= round-2 fallback path (used only if ws too small) ========
__global__ __launch_bounds__(64) void vq_norms(const float* __restrict__ cb,
                                               float* __restrict__ q,
                                               int* __restrict__ counts) {
    int k = blockIdx.x;
    int lane = threadIdx.x;
    float4 e4 = *(const float4*)(cb + (size_t)k * DIM + lane * 4);
    double s = (double)e4.x * e4.x + (double)e4.y * e4.y
             + (double)e4.z * e4.z + (double)e4.w * e4.w;
    #pragma unroll
    for (int off = 32; off > 0; off >>= 1) s += __shfl_down(s, off);
    if (lane == 0) { q[k] = (float)s; counts[k] = 0; }
}

__global__ __launch_bounds__(256) void vq_main_r2(const float* __restrict__ z,
                                                  const float* __restrict__ cb,
                                                  const float* __restrict__ q,
                                                  float* __restrict__ out_zq,
                                                  float* __restrict__ out_idx,
                                                  int* __restrict__ counts,
                                                  float* __restrict__ lpart) {
    __shared__ float zt[32][LDSTRIDE];
    __shared__ float sbest[32][8];
    __shared__ int   kbest[32][8];
    __shared__ int   sel[32];
    __shared__ float lred[256];

    const int blk = blockIdx.x;
    const int b   = blk >> 5;
    const int h   = blk & 31;
    const int tid = threadIdx.x;
    const float* zb = z + (size_t)b * 262144 + (size_t)h * 32;

    #pragma unroll
    for (int it = 0; it < 32; ++it) {
        int e = it * 256 + tid;
        int d = e >> 5, ww = e & 31;
        zt[ww][d] = zb[(size_t)d * 1024 + ww];
    }
    __syncthreads();

    const int r    = tid >> 3;
    const int lane = tid & 7;
    const float4* zr = (const float4*)(&zt[r][0]);

    double pa = 0.0;
    #pragma unroll 8
    for (int i = 0; i < 32; ++i) {
        float v = zt[r][lane + 8 * i];
        pa += (double)v * (double)v;
    }
    pa += __shfl_down(pa, 4, 8);
    pa += __shfl_down(pa, 2, 8);
    pa += __shfl_down(pa, 1, 8);
    pa = __shfl(pa, 0, 8);
    const float A = (float)pa;

    float best = INFINITY;
    int   bk   = 0;
    for (int j = 0; j < 64; ++j) {
        const int kk1 = lane + 8 * j;
        const int kk2 = kk1 + 512;
        const float4* e1 = (const float4*)(cb + (size_t)kk1 * DIM);
        const float4* e2 = (const float4*)(cb + (size_t)kk2 * DIM);
        float a1x = 0.f, a1y = 0.f, a1z = 0.f, a1w = 0.f;
        float a2x = 0.f, a2y = 0.f, a2z = 0.f, a2w = 0.f;
        #pragma unroll 16
        for (int d4 = 0; d4 < DIM / 4; ++d4) {
            float4 zv = zr[d4];
            float4 v1 = e1[d4];
            float4 v2 = e2[d4];
            a1x = fmaf(zv.x, v1.x, a1x); a1y = fmaf(zv.y, v1.y, a1y);
            a1z = fmaf(zv.z, v1.z, a1z); a1w = fmaf(zv.w, v1.w, a1w);
            a2x = fmaf(zv.x, v2.x, a2x); a2y = fmaf(zv.y, v2.y, a2y);
            a2z = fmaf(zv.z, v2.z, a2z); a2w = fmaf(zv.w, v2.w, a2w);
        }
        float dot1 = __fadd_rn(__fadd_rn(a1x, a1y), __fadd_rn(a1z, a1w));
        float dot2 = __fadd_rn(__fadd_rn(a2x, a2y), __fadd_rn(a2z, a2w));
        float sc1 = __fsub_rn(__fadd_rn(A, q[kk1]), __fmul_rn(2.f, dot1));
        float sc2 = __fsub_rn(__fadd_rn(A, q[kk2]), __fmul_rn(2.f, dot2));
        if (sc1 < best || (sc1 == best && kk1 < bk)) { best = sc1; bk = kk1; }
        if (sc2 < best || (sc2 == best && kk2 < bk)) { best = sc2; bk = kk2; }
    }
    sbest[r][lane] = best;
    kbest[r][lane] = bk;
    __syncthreads();

    if (tid < 32) {
        float bb = sbest[tid][0];
        int   bi = kbest[tid][0];
        #pragma unroll
        for (int ll = 1; ll < 8; ++ll) {
            float s = sbest[tid][ll]; int kk = kbest[tid][ll];
            if (s < bb || (s == bb && kk < bi)) { bb = s; bi = kk; }
        }
        sel[tid] = bi;
        out_idx[blk * 32 + tid] = (float)bi;
        atomicAdd(&counts[bi], 1);
    }
    __syncthreads();

    float lacc = 0.f;
    float* ob = out_zq + (size_t)b * 262144 + (size_t)h * 32;
    #pragma unroll
    for (int it = 0; it < 32; ++it) {
        int e = it * 256 + tid;
        int c = e >> 5, ww = e & 31;
        float cv = cb[(size_t)sel[ww] * DIM + c];
        float dz = cv - zt[ww][c];
        lacc = fmaf(dz, dz, lacc);
        ob[(size_t)c * 1024 + ww] = cv;
    }
    lred[tid] = lacc;
    __syncthreads();
    #pragma unroll
    for (int s = 128; s > 0; s >>= 1) {
        if (tid < s) lred[tid] += lred[tid + s];
        __syncthreads();
    }
    if (tid == 0) lpart[blk] = lred[0];
}

extern "C" void kernel_launch(void* const* d_in, const int* in_sizes, int n_in,
                              void* d_out, int out_size, void* d_ws, size_t ws_size,
                              hipStream_t stream) {
    const float* z  = (const float*)d_in[0];          // [64,256,32,32]
    const float* cb = (const float*)d_in[1];          // [1024,256]

    float* out_zq      = (float*)d_out;               // 16777216
    float* out_idx     = out_zq + ZQ_ELEMS;           // 65536
    float* out_scalars = out_idx + NROWS;             // loss, perplexity

    float*  q      = (float*)d_ws;                    // 1024 f32
    int*    counts = (int*)(q + NCODES);              // 1024 i32
    float*  lpart  = (float*)(counts + NCODES);       // 2048 f32
    ushort* cbf    = (ushort*)((char*)d_ws + 16384);  // 512 KB frag-linear f16

    bool mfma_ok = ws_size >= (size_t)(16384 + NCODES * DIM * 2);

    if (mfma_ok) {
        vq_prep<<<NCODES, 64, 0, stream>>>(cb, q, counts, cbf);
        vq_mfma4<<<NROWS / 32, 256, 0, stream>>>(z, cb, cbf, q, out_zq, out_idx, counts, lpart);
        vq_finalize<<<1, 256, 0, stream>>>(lpart, counts, out_scalars, NROWS / 32);
    } else {
        vq_norms<<<NCODES, 64, 0, stream>>>(cb, q, counts);
        vq_main_r2<<<NROWS / 32, 256, 0, stream>>>(z, cb, q, out_zq, out_idx, counts, lpart);
        vq_finalize<<<1, 256, 0, stream>>>(lpart, counts, out_scalars, NROWS / 32);
    }
}